// Round 5
// baseline (660.231 us; speedup 1.0000x reference)
//
#include <hip/hip_runtime.h>

#define N_NODES   50000
#define N_EDGES   800000
#define DIM       64
#define NUM_GRAPHS 512
#define EPS       1e-5f

#define SB   1024
#define NSB  ((N_NODES + SB - 1) / SB)   // 49 scan blocks

// ---------------------------------------------------------------- zero init
__global__ void k_zero(int* __restrict__ deg, float* __restrict__ sums2,
                       float* __restrict__ sums3, float* __restrict__ pooled) {
    int i = blockIdx.x * 256 + threadIdx.x;
    if (i < N_NODES) deg[i] = 0;
    if (i < 128) { sums2[i] = 0.f; sums3[i] = 0.f; }
    if (i < NUM_GRAPHS * DIM) pooled[i] = 0.f;
}

// ---------------------------------------------------------------- degree count
__global__ void k_count(const int* __restrict__ dst, int* __restrict__ deg) {
    int i = blockIdx.x * 256 + threadIdx.x;
    if (i < N_EDGES) atomicAdd(&deg[dst[i]], 1);
}

// ---------------------------------------------------------------- scan phase 1: per-block sums
__global__ void __launch_bounds__(1024)
k_scan1(const int* __restrict__ deg, int* __restrict__ bsum) {
    __shared__ int red[16];
    int t = threadIdx.x;
    int i = blockIdx.x * SB + t;
    int v = (i < N_NODES) ? deg[i] : 0;
#pragma unroll
    for (int d = 32; d; d >>= 1) v += __shfl_down(v, d, 64);
    if ((t & 63) == 0) red[t >> 6] = v;
    __syncthreads();
    if (t < 16) {
        int s = red[t];
#pragma unroll
        for (int d = 8; d; d >>= 1) s += __shfl_down(s, d, 16);
        if (t == 0) bsum[blockIdx.x] = s;
    }
}

// ---------------------------------------------------------------- scan phase 2: scan of 49 block sums (1 wave)
__global__ void k_scan2(const int* __restrict__ bsum, int* __restrict__ boff) {
    int t = threadIdx.x;   // 64 threads
    int v = (t < NSB) ? bsum[t] : 0;
    int orig = v;
#pragma unroll
    for (int d = 1; d < 64; d <<= 1) {
        int u = __shfl_up(v, d, 64);
        if (t >= d) v += u;
    }
    if (t < NSB) boff[t] = v - orig;   // exclusive prefix
}

// ---------------------------------------------------------------- scan phase 3: full exclusive scan, write off/cursor/invd
__global__ void __launch_bounds__(1024)
k_scan3(const int* __restrict__ deg, const int* __restrict__ boff,
        int* __restrict__ off, int* __restrict__ cursor, float* __restrict__ invd) {
    __shared__ int wsum[16];
    int t = threadIdx.x, lane = t & 63, w = t >> 6;
    int i = blockIdx.x * SB + t;
    int d = (i < N_NODES) ? deg[i] : 0;
    int v = d;
#pragma unroll
    for (int s = 1; s < 64; s <<= 1) {
        int u = __shfl_up(v, s, 64);
        if (lane >= s) v += u;
    }
    if (lane == 63) wsum[w] = v;
    __syncthreads();
    if (t < 16) {
        int x = wsum[t];
#pragma unroll
        for (int s = 1; s < 16; s <<= 1) {
            int u = __shfl_up(x, s, 16);
            if (t >= s) x += u;
        }
        wsum[t] = x;   // inclusive across waves (lockstep within wave 0)
    }
    __syncthreads();
    if (i < N_NODES) {
        int ex = boff[blockIdx.x] + ((w > 0) ? wsum[w - 1] : 0) + v - d;
        off[i] = ex;
        cursor[i] = ex;
        invd[i] = 1.0f / (float)max(d, 1);
        if (i == N_NODES - 1) off[N_NODES] = ex + d;
    }
}

// ---------------------------------------------------------------- CSR scatter (direct; 47us, write-amp bound but near ceiling)
__global__ void k_scatter(const int* __restrict__ src, const int* __restrict__ dst,
                          int* __restrict__ cursor, int* __restrict__ csr_src) {
    int i = blockIdx.x * 256 + threadIdx.x;
    if (i < N_EDGES) {
        int p = atomicAdd(&cursor[dst[i]], 1);
        csr_src[p] = src[i];
    }
}

// ---------------------------------------------------------------- fp32 -> bf16 RNE
__device__ inline unsigned f2bf(float f) {
    unsigned u = __float_as_uint(f);
    return (u + 0x7FFFu + ((u >> 16) & 1u)) >> 16;
}

// ---------------------------------------------------------------- dual GEMM, weights in registers
// xs = BN(x)@Ws + b (fp32) ; xnh = bf16-packed BN(x)@Wn.  32 rows/block.
#define GR 32   // rows per block
template<bool BN>
__global__ void __launch_bounds__(256, 3)
k_gemm(const float* __restrict__ x, const float* __restrict__ Ws,
       const float* __restrict__ Wn, const float* __restrict__ bias,
       const float* __restrict__ bn_a, const float* __restrict__ bn_c,
       float* __restrict__ xs, unsigned* __restrict__ xnh) {
    __shared__ float sX[GR][DIM];
    int tid = threadIdx.x;
    int lane = tid & 63, w = tid >> 6;

    // per-thread column of each weight matrix, fully unrolled -> registers
    float wsr[DIM], wnr[DIM];
#pragma unroll
    for (int k = 0; k < DIM; ++k) {
        wsr[k] = Ws[k * DIM + lane];
        wnr[k] = Wn[k * DIM + lane];
    }
    float bv = bias[lane];
    float aL = 1.f, cL = 0.f;
    if constexpr (BN) { aL = bn_a[lane]; cL = bn_c[lane]; }

    int rowBase = blockIdx.x * GR;
#pragma unroll
    for (int r = 0; r < GR / 4; ++r) {
        int row = r * 4 + w;
        int gr = rowBase + row;
        float v = (gr < N_NODES) ? x[gr * DIM + lane] : 0.f;
        sX[row][lane] = fmaf(v, aL, cL);
    }
    __syncthreads();

    // wave w computes rows [w*8, w*8+8)
#pragma unroll
    for (int r = 0; r < 8; ++r) {
        int row = w * 8 + r;
        float s = bv, n = 0.f;
#pragma unroll
        for (int kg = 0; kg < DIM / 4; ++kg) {
            float4 xv = *reinterpret_cast<const float4*>(&sX[row][kg * 4]);
            s = fmaf(xv.x, wsr[kg * 4 + 0], s); n = fmaf(xv.x, wnr[kg * 4 + 0], n);
            s = fmaf(xv.y, wsr[kg * 4 + 1], s); n = fmaf(xv.y, wnr[kg * 4 + 1], n);
            s = fmaf(xv.z, wsr[kg * 4 + 2], s); n = fmaf(xv.z, wnr[kg * 4 + 2], n);
            s = fmaf(xv.w, wsr[kg * 4 + 3], s); n = fmaf(xv.w, wnr[kg * 4 + 3], n);
        }
        int grow = rowBase + row;
        float nOther = __shfl_xor(n, 1, 64);   // partner channel's value
        if (grow < N_NODES) {
            xs[grow * DIM + lane] = s;
            if (!(lane & 1)) {                 // even lane packs (2p, 2p+1)
                unsigned word = (f2bf(nOther) << 16) | f2bf(n);
                xnh[grow * 32 + (lane >> 1)] = word;
            }
        }
    }
}

// ---------------------------------------------------------------- aggregate: h = relu(xs + inv_deg * sum_{src} xn[src])
// xn is bf16-packed (32 words/row = 128B). Wave = 1 dst row; two 32-lane
// halves process alternating edges; combine via shfl_xor(32).
template<bool POOL>
__global__ void __launch_bounds__(256)
k_agg(const float* __restrict__ xs, const unsigned* __restrict__ xnh,
      const int* __restrict__ off, const int* __restrict__ csr_src,
      const float* __restrict__ inv_deg, const int* __restrict__ gind,
      float* __restrict__ h, float* __restrict__ pooled) {
    int tid = threadIdx.x;
    int w = tid >> 6;            // wave index = row within block
    int lane = tid & 63;
    int hw = lane >> 5;          // which edge of the pair
    int p = lane & 31;           // channel pair index
    int row = blockIdx.x * 4 + w;
    if (row >= N_NODES) return;
    int jb = off[row], je = off[row + 1];
    float ax = 0.f, ay = 0.f;
    for (int j = jb + hw; j < je; j += 2) {
        int s = csr_src[j];
        unsigned wd = xnh[s * 32 + p];
        ax += __uint_as_float(wd << 16);
        ay += __uint_as_float(wd & 0xFFFF0000u);
    }
    ax += __shfl_xor(ax, 32, 64);
    ay += __shfl_xor(ay, 32, 64);
    if (hw == 0) {
        float id = inv_deg[row];
        float2 xv = *reinterpret_cast<const float2*>(&xs[row * DIM + 2 * p]);
        float vx = fmaxf(fmaf(ax, id, xv.x), 0.f);
        float vy = fmaxf(fmaf(ay, id, xv.y), 0.f);
        *reinterpret_cast<float2*>(&h[row * DIM + 2 * p]) = make_float2(vx, vy);
        if constexpr (POOL) {
            int g = gind[row];
            atomicAdd(&pooled[g * DIM + 2 * p], vx);
            atomicAdd(&pooled[g * DIM + 2 * p + 1], vy);
        }
    }
}

// ---------------------------------------------------------------- BN stats (sum, sumsq per channel)
__global__ void __launch_bounds__(256)
k_stats(const float* __restrict__ h, float* __restrict__ sums) {
    int lane = threadIdx.x & 63, w = threadIdx.x >> 6;
    float s = 0.f, q = 0.f;
    for (int r = blockIdx.x * 4 + w; r < N_NODES; r += gridDim.x * 4) {
        float v = h[r * DIM + lane];
        s += v;
        q = fmaf(v, v, q);
    }
    __shared__ float sS[4][DIM], sQ[4][DIM];
    sS[w][lane] = s; sQ[w][lane] = q;
    __syncthreads();
    if (w == 0) {
        float ts = sS[0][lane] + sS[1][lane] + sS[2][lane] + sS[3][lane];
        float tq = sQ[0][lane] + sQ[1][lane] + sQ[2][lane] + sQ[3][lane];
        atomicAdd(&sums[lane], ts);
        atomicAdd(&sums[DIM + lane], tq);
    }
}

// ---------------------------------------------------------------- BN finalize: a = g*rsqrt(var+eps), c = be - mean*a
__global__ void k_bnfin(const float* __restrict__ sums, const float* __restrict__ g,
                        const float* __restrict__ be, float* __restrict__ a,
                        float* __restrict__ c) {
    int t = threadIdx.x;  // 64 threads
    float m = sums[t] * (1.0f / N_NODES);
    float q = sums[DIM + t] * (1.0f / N_NODES);
    float v = q - m * m;
    float inv = 1.0f / sqrtf(v + EPS);
    float av = g[t] * inv;
    a[t] = av;
    c[t] = be[t] - m * av;
}

// ---------------------------------------------------------------- MLP head (one block per graph)
__global__ void __launch_bounds__(128)
k_mlp(const float* __restrict__ pooled,
      const float* __restrict__ W1, const float* __restrict__ b1,
      const float* __restrict__ W2, const float* __restrict__ b2,
      const float* __restrict__ W3, const float* __restrict__ b3,
      float* __restrict__ out) {
    __shared__ float sp[64], s1[128], s2[64];
    int g = blockIdx.x, t = threadIdx.x;
    if (t < 64) sp[t] = pooled[g * 64 + t];
    __syncthreads();
    {
        float acc = b1[t];
#pragma unroll
        for (int k = 0; k < 64; ++k) acc = fmaf(sp[k], W1[k * 128 + t], acc);
        s1[t] = fmaxf(acc, 0.f);
    }
    __syncthreads();
    if (t < 64) {
        float acc = b2[t];
#pragma unroll
        for (int k = 0; k < 128; ++k) acc = fmaf(s1[k], W2[k * 64 + t], acc);
        s2[t] = fmaxf(acc, 0.f);
    }
    __syncthreads();
    if (t < 10) {
        float acc = b3[t];
#pragma unroll
        for (int k = 0; k < 64; ++k) acc = fmaf(s2[k], W3[k * 10 + t], acc);
        out[g * 10 + t] = acc;
    }
}

// ---------------------------------------------------------------- launch
extern "C" void kernel_launch(void* const* d_in, const int* in_sizes, int n_in,
                              void* d_out, int out_size, void* d_ws, size_t ws_size,
                              hipStream_t stream) {
    const float* x0   = (const float*)d_in[0];
    const int* e_src  = (const int*)d_in[1];
    const int* e_dst  = (const int*)d_in[2];
    const int* gind   = (const int*)d_in[3];
    // d_in[4] = labels (unused)
    const float* Ws1 = (const float*)d_in[5],  *Wn1 = (const float*)d_in[6],  *b1 = (const float*)d_in[7];
    const float* Ws2 = (const float*)d_in[8],  *Wn2 = (const float*)d_in[9],  *b2 = (const float*)d_in[10];
    const float* Ws3 = (const float*)d_in[11], *Wn3 = (const float*)d_in[12], *b3 = (const float*)d_in[13];
    const float* g2  = (const float*)d_in[14], *be2 = (const float*)d_in[15];
    const float* g3  = (const float*)d_in[16], *be3 = (const float*)d_in[17];
    const float* fcW1 = (const float*)d_in[18], *fcb1 = (const float*)d_in[19];
    const float* fcW2 = (const float*)d_in[20], *fcb2 = (const float*)d_in[21];
    const float* fcW3 = (const float*)d_in[22], *fcb3 = (const float*)d_in[23];
    float* out = (float*)d_out;

    char* p = (char*)d_ws;
    auto carve = [&](size_t bytes) { void* r = (void*)p; p += (bytes + 255) & ~(size_t)255; return r; };
    int*   deg     = (int*)  carve(N_NODES * 4);
    int*   off     = (int*)  carve((N_NODES + 1) * 4);
    int*   cursor  = (int*)  carve(N_NODES * 4);
    int*   csr_src = (int*)  carve(N_EDGES * 4);
    float* invd    = (float*)carve(N_NODES * 4);
    int*   bsum    = (int*)  carve(NSB * 4);
    int*   boff    = (int*)  carve((NSB + 1) * 4);
    float* sums2   = (float*)carve(128 * 4);
    float* sums3   = (float*)carve(128 * 4);
    float* a2      = (float*)carve(64 * 4);
    float* c2      = (float*)carve(64 * 4);
    float* a3      = (float*)carve(64 * 4);
    float* c3      = (float*)carve(64 * 4);
    float* pooled  = (float*)carve(NUM_GRAPHS * DIM * 4);
    float* bufH    = (float*)carve((size_t)N_NODES * DIM * 4);
    float* bufXS   = (float*)carve((size_t)N_NODES * DIM * 4);
    unsigned* bufXN = (unsigned*)carve((size_t)N_NODES * 32 * 4);   // bf16-packed

    const int EB = (N_EDGES + 255) / 256;           // 3125
    const int GB = (N_NODES + GR - 1) / GR;         // 1563 (gemm: 32 rows/block)
    const int AB = (N_NODES + 3) / 4;               // 12500 (agg: 4 rows/block)

    k_zero<<<(N_NODES + 255) / 256, 256, 0, stream>>>(deg, sums2, sums3, pooled);
    k_count<<<EB, 256, 0, stream>>>(e_dst, deg);
    k_scan1<<<NSB, SB, 0, stream>>>(deg, bsum);
    k_scan2<<<1, 64, 0, stream>>>(bsum, boff);
    k_scan3<<<NSB, SB, 0, stream>>>(deg, boff, off, cursor, invd);
    k_scatter<<<EB, 256, 0, stream>>>(e_src, e_dst, cursor, csr_src);

    // Layer 1 (no BN on input)
    k_gemm<false><<<GB, 256, 0, stream>>>(x0, Ws1, Wn1, b1, nullptr, nullptr, bufXS, bufXN);
    k_agg<false><<<AB, 256, 0, stream>>>(bufXS, bufXN, off, csr_src, invd, nullptr, bufH, nullptr);

    // BN2 stats + Layer 2
    k_stats<<<240, 256, 0, stream>>>(bufH, sums2);
    k_bnfin<<<1, 64, 0, stream>>>(sums2, g2, be2, a2, c2);
    k_gemm<true><<<GB, 256, 0, stream>>>(bufH, Ws2, Wn2, b2, a2, c2, bufXS, bufXN);
    k_agg<false><<<AB, 256, 0, stream>>>(bufXS, bufXN, off, csr_src, invd, nullptr, bufH, nullptr);

    // BN3 stats + Layer 3 (fused pooling)
    k_stats<<<240, 256, 0, stream>>>(bufH, sums3);
    k_bnfin<<<1, 64, 0, stream>>>(sums3, g3, be3, a3, c3);
    k_gemm<true><<<GB, 256, 0, stream>>>(bufH, Ws3, Wn3, b3, a3, c3, bufXS, bufXN);
    k_agg<true><<<AB, 256, 0, stream>>>(bufXS, bufXN, off, csr_src, invd, gind, bufH, pooled);

    // MLP head
    k_mlp<<<NUM_GRAPHS, 128, 0, stream>>>(pooled, fcW1, fcb1, fcW2, fcb2, fcW3, fcb3, out);
}

// Round 6
// 392.105 us; speedup vs baseline: 1.6838x; 1.6838x over previous
//
#include <hip/hip_runtime.h>

#define N_NODES   50000
#define N_EDGES   800000
#define DIM       64
#define NUM_GRAPHS 512
#define EPS       1e-5f

#define SB   1024
#define NSB  ((N_NODES + SB - 1) / SB)   // 49 scan blocks

// ---------------------------------------------------------------- zero init
__global__ void k_zero(int* __restrict__ deg, float* __restrict__ sums2,
                       float* __restrict__ sums3, float* __restrict__ pooled) {
    int i = blockIdx.x * 256 + threadIdx.x;
    if (i < N_NODES) deg[i] = 0;
    if (i < 128) { sums2[i] = 0.f; sums3[i] = 0.f; }
    if (i < NUM_GRAPHS * DIM) pooled[i] = 0.f;
}

// ---------------------------------------------------------------- degree count
__global__ void k_count(const int* __restrict__ dst, int* __restrict__ deg) {
    int i = blockIdx.x * 256 + threadIdx.x;
    if (i < N_EDGES) atomicAdd(&deg[dst[i]], 1);
}

// ---------------------------------------------------------------- scan phase 1: per-block sums
__global__ void __launch_bounds__(1024)
k_scan1(const int* __restrict__ deg, int* __restrict__ bsum) {
    __shared__ int red[16];
    int t = threadIdx.x;
    int i = blockIdx.x * SB + t;
    int v = (i < N_NODES) ? deg[i] : 0;
#pragma unroll
    for (int d = 32; d; d >>= 1) v += __shfl_down(v, d, 64);
    if ((t & 63) == 0) red[t >> 6] = v;
    __syncthreads();
    if (t < 16) {
        int s = red[t];
#pragma unroll
        for (int d = 8; d; d >>= 1) s += __shfl_down(s, d, 16);
        if (t == 0) bsum[blockIdx.x] = s;
    }
}

// ---------------------------------------------------------------- scan phase 2: scan of 49 block sums (1 wave)
__global__ void k_scan2(const int* __restrict__ bsum, int* __restrict__ boff) {
    int t = threadIdx.x;   // 64 threads
    int v = (t < NSB) ? bsum[t] : 0;
    int orig = v;
#pragma unroll
    for (int d = 1; d < 64; d <<= 1) {
        int u = __shfl_up(v, d, 64);
        if (t >= d) v += u;
    }
    if (t < NSB) boff[t] = v - orig;   // exclusive prefix
}

// ---------------------------------------------------------------- scan phase 3: full exclusive scan, write off/cursor/invd
__global__ void __launch_bounds__(1024)
k_scan3(const int* __restrict__ deg, const int* __restrict__ boff,
        int* __restrict__ off, int* __restrict__ cursor, float* __restrict__ invd) {
    __shared__ int wsum[16];
    int t = threadIdx.x, lane = t & 63, w = t >> 6;
    int i = blockIdx.x * SB + t;
    int d = (i < N_NODES) ? deg[i] : 0;
    int v = d;
#pragma unroll
    for (int s = 1; s < 64; s <<= 1) {
        int u = __shfl_up(v, s, 64);
        if (lane >= s) v += u;
    }
    if (lane == 63) wsum[w] = v;
    __syncthreads();
    if (t < 16) {
        int x = wsum[t];
#pragma unroll
        for (int s = 1; s < 16; s <<= 1) {
            int u = __shfl_up(x, s, 16);
            if (t >= s) x += u;
        }
        wsum[t] = x;   // inclusive across waves (lockstep within wave 0)
    }
    __syncthreads();
    if (i < N_NODES) {
        int ex = boff[blockIdx.x] + ((w > 0) ? wsum[w - 1] : 0) + v - d;
        off[i] = ex;
        cursor[i] = ex;
        invd[i] = 1.0f / (float)max(d, 1);
        if (i == N_NODES - 1) off[N_NODES] = ex + d;
    }
}

// ---------------------------------------------------------------- CSR scatter (direct)
__global__ void k_scatter(const int* __restrict__ src, const int* __restrict__ dst,
                          int* __restrict__ cursor, int* __restrict__ csr_src) {
    int i = blockIdx.x * 256 + threadIdx.x;
    if (i < N_EDGES) {
        int p = atomicAdd(&cursor[dst[i]], 1);
        csr_src[p] = src[i];
    }
}

// ---------------------------------------------------------------- fp32 -> bf16 RNE
__device__ inline unsigned short f2bf(float f) {
    unsigned u = __float_as_uint(f);
    return (unsigned short)((u + 0x7FFFu + ((u >> 16) & 1u)) >> 16);
}

// ---------------------------------------------------------------- dual GEMM, weights in registers
// xs = BN(x)@Ws + b (fp32) ; xnh16 = bf16 BN(x)@Wn (ushort/lane, coalesced).
#define GR 32   // rows per block
template<bool BN>
__global__ void __launch_bounds__(256)
k_gemm(const float* __restrict__ x, const float* __restrict__ Ws,
       const float* __restrict__ Wn, const float* __restrict__ bias,
       const float* __restrict__ bn_a, const float* __restrict__ bn_c,
       float* __restrict__ xs, unsigned short* __restrict__ xnh16) {
    __shared__ float sX[GR][DIM];
    int tid = threadIdx.x;
    int lane = tid & 63, w = tid >> 6;

    // per-thread column of each weight matrix, fully unrolled -> registers
    float wsr[DIM], wnr[DIM];
#pragma unroll
    for (int k = 0; k < DIM; ++k) {
        wsr[k] = Ws[k * DIM + lane];
        wnr[k] = Wn[k * DIM + lane];
    }
    float bv = bias[lane];
    float aL = 1.f, cL = 0.f;
    if constexpr (BN) { aL = bn_a[lane]; cL = bn_c[lane]; }

    int rowBase = blockIdx.x * GR;
#pragma unroll
    for (int r = 0; r < GR / 4; ++r) {
        int row = r * 4 + w;
        int gr = rowBase + row;
        float v = (gr < N_NODES) ? x[gr * DIM + lane] : 0.f;
        sX[row][lane] = fmaf(v, aL, cL);
    }
    __syncthreads();

    // wave w computes rows [w*8, w*8+8)
#pragma unroll
    for (int r = 0; r < 8; ++r) {
        int row = w * 8 + r;
        float s = bv, n = 0.f;
#pragma unroll
        for (int kg = 0; kg < DIM / 4; ++kg) {
            float4 xv = *reinterpret_cast<const float4*>(&sX[row][kg * 4]);
            s = fmaf(xv.x, wsr[kg * 4 + 0], s); n = fmaf(xv.x, wnr[kg * 4 + 0], n);
            s = fmaf(xv.y, wsr[kg * 4 + 1], s); n = fmaf(xv.y, wnr[kg * 4 + 1], n);
            s = fmaf(xv.z, wsr[kg * 4 + 2], s); n = fmaf(xv.z, wnr[kg * 4 + 2], n);
            s = fmaf(xv.w, wsr[kg * 4 + 3], s); n = fmaf(xv.w, wnr[kg * 4 + 3], n);
        }
        int grow = rowBase + row;
        if (grow < N_NODES) {
            xs[grow * DIM + lane] = s;
            xnh16[grow * DIM + lane] = f2bf(n);   // 64x2B = one 128B coalesced store
        }
    }
}

// ---------------------------------------------------------------- aggregate: h = relu(xs + inv_deg * sum_{src} xn[src])
// xn is bf16 (64 ushort/row = 128B, read as 32 words). Wave = 1 dst row;
// two 32-lane halves process alternating edges; combine via shfl_xor(32).
template<bool POOL>
__global__ void __launch_bounds__(256)
k_agg(const float* __restrict__ xs, const unsigned* __restrict__ xnh,
      const int* __restrict__ off, const int* __restrict__ csr_src,
      const float* __restrict__ inv_deg, const int* __restrict__ gind,
      float* __restrict__ h, float* __restrict__ pooled) {
    int tid = threadIdx.x;
    int w = tid >> 6;            // wave index = row within block
    int lane = tid & 63;
    int hw = lane >> 5;          // which edge of the pair
    int p = lane & 31;           // channel pair index
    int row = blockIdx.x * 4 + w;
    if (row >= N_NODES) return;
    int jb = off[row], je = off[row + 1];
    float ax = 0.f, ay = 0.f;
    for (int j = jb + hw; j < je; j += 2) {
        int s = csr_src[j];
        unsigned wd = xnh[s * 32 + p];
        ax += __uint_as_float(wd << 16);          // channel 2p (low ushort)
        ay += __uint_as_float(wd & 0xFFFF0000u);  // channel 2p+1 (high ushort)
    }
    ax += __shfl_xor(ax, 32, 64);
    ay += __shfl_xor(ay, 32, 64);
    if (hw == 0) {
        float id = inv_deg[row];
        float2 xv = *reinterpret_cast<const float2*>(&xs[row * DIM + 2 * p]);
        float vx = fmaxf(fmaf(ax, id, xv.x), 0.f);
        float vy = fmaxf(fmaf(ay, id, xv.y), 0.f);
        *reinterpret_cast<float2*>(&h[row * DIM + 2 * p]) = make_float2(vx, vy);
        if constexpr (POOL) {
            int g = gind[row];
            atomicAdd(&pooled[g * DIM + 2 * p], vx);
            atomicAdd(&pooled[g * DIM + 2 * p + 1], vy);
        }
    }
}

// ---------------------------------------------------------------- BN stats (sum, sumsq per channel)
__global__ void __launch_bounds__(256)
k_stats(const float* __restrict__ h, float* __restrict__ sums) {
    int lane = threadIdx.x & 63, w = threadIdx.x >> 6;
    float s = 0.f, q = 0.f;
    for (int r = blockIdx.x * 4 + w; r < N_NODES; r += gridDim.x * 4) {
        float v = h[r * DIM + lane];
        s += v;
        q = fmaf(v, v, q);
    }
    __shared__ float sS[4][DIM], sQ[4][DIM];
    sS[w][lane] = s; sQ[w][lane] = q;
    __syncthreads();
    if (w == 0) {
        float ts = sS[0][lane] + sS[1][lane] + sS[2][lane] + sS[3][lane];
        float tq = sQ[0][lane] + sQ[1][lane] + sQ[2][lane] + sQ[3][lane];
        atomicAdd(&sums[lane], ts);
        atomicAdd(&sums[DIM + lane], tq);
    }
}

// ---------------------------------------------------------------- BN finalize: a = g*rsqrt(var+eps), c = be - mean*a
__global__ void k_bnfin(const float* __restrict__ sums, const float* __restrict__ g,
                        const float* __restrict__ be, float* __restrict__ a,
                        float* __restrict__ c) {
    int t = threadIdx.x;  // 64 threads
    float m = sums[t] * (1.0f / N_NODES);
    float q = sums[DIM + t] * (1.0f / N_NODES);
    float v = q - m * m;
    float inv = 1.0f / sqrtf(v + EPS);
    float av = g[t] * inv;
    a[t] = av;
    c[t] = be[t] - m * av;
}

// ---------------------------------------------------------------- MLP head (one block per graph)
__global__ void __launch_bounds__(128)
k_mlp(const float* __restrict__ pooled,
      const float* __restrict__ W1, const float* __restrict__ b1,
      const float* __restrict__ W2, const float* __restrict__ b2,
      const float* __restrict__ W3, const float* __restrict__ b3,
      float* __restrict__ out) {
    __shared__ float sp[64], s1[128], s2[64];
    int g = blockIdx.x, t = threadIdx.x;
    if (t < 64) sp[t] = pooled[g * 64 + t];
    __syncthreads();
    {
        float acc = b1[t];
#pragma unroll
        for (int k = 0; k < 64; ++k) acc = fmaf(sp[k], W1[k * 128 + t], acc);
        s1[t] = fmaxf(acc, 0.f);
    }
    __syncthreads();
    if (t < 64) {
        float acc = b2[t];
#pragma unroll
        for (int k = 0; k < 128; ++k) acc = fmaf(s1[k], W2[k * 64 + t], acc);
        s2[t] = fmaxf(acc, 0.f);
    }
    __syncthreads();
    if (t < 10) {
        float acc = b3[t];
#pragma unroll
        for (int k = 0; k < 64; ++k) acc = fmaf(s2[k], W3[k * 10 + t], acc);
        out[g * 10 + t] = acc;
    }
}

// ---------------------------------------------------------------- launch
extern "C" void kernel_launch(void* const* d_in, const int* in_sizes, int n_in,
                              void* d_out, int out_size, void* d_ws, size_t ws_size,
                              hipStream_t stream) {
    const float* x0   = (const float*)d_in[0];
    const int* e_src  = (const int*)d_in[1];
    const int* e_dst  = (const int*)d_in[2];
    const int* gind   = (const int*)d_in[3];
    // d_in[4] = labels (unused)
    const float* Ws1 = (const float*)d_in[5],  *Wn1 = (const float*)d_in[6],  *b1 = (const float*)d_in[7];
    const float* Ws2 = (const float*)d_in[8],  *Wn2 = (const float*)d_in[9],  *b2 = (const float*)d_in[10];
    const float* Ws3 = (const float*)d_in[11], *Wn3 = (const float*)d_in[12], *b3 = (const float*)d_in[13];
    const float* g2  = (const float*)d_in[14], *be2 = (const float*)d_in[15];
    const float* g3  = (const float*)d_in[16], *be3 = (const float*)d_in[17];
    const float* fcW1 = (const float*)d_in[18], *fcb1 = (const float*)d_in[19];
    const float* fcW2 = (const float*)d_in[20], *fcb2 = (const float*)d_in[21];
    const float* fcW3 = (const float*)d_in[22], *fcb3 = (const float*)d_in[23];
    float* out = (float*)d_out;

    char* p = (char*)d_ws;
    auto carve = [&](size_t bytes) { void* r = (void*)p; p += (bytes + 255) & ~(size_t)255; return r; };
    int*   deg     = (int*)  carve(N_NODES * 4);
    int*   off     = (int*)  carve((N_NODES + 1) * 4);
    int*   cursor  = (int*)  carve(N_NODES * 4);
    int*   csr_src = (int*)  carve(N_EDGES * 4);
    float* invd    = (float*)carve(N_NODES * 4);
    int*   bsum    = (int*)  carve(NSB * 4);
    int*   boff    = (int*)  carve((NSB + 1) * 4);
    float* sums2   = (float*)carve(128 * 4);
    float* sums3   = (float*)carve(128 * 4);
    float* a2      = (float*)carve(64 * 4);
    float* c2      = (float*)carve(64 * 4);
    float* a3      = (float*)carve(64 * 4);
    float* c3      = (float*)carve(64 * 4);
    float* pooled  = (float*)carve(NUM_GRAPHS * DIM * 4);
    float* bufH    = (float*)carve((size_t)N_NODES * DIM * 4);
    float* bufXS   = (float*)carve((size_t)N_NODES * DIM * 4);
    unsigned* bufXN = (unsigned*)carve((size_t)N_NODES * 32 * 4);   // bf16-packed

    const int EB = (N_EDGES + 255) / 256;           // 3125
    const int GB = (N_NODES + GR - 1) / GR;         // 1563 (gemm: 32 rows/block)
    const int AB = (N_NODES + 3) / 4;               // 12500 (agg: 4 rows/block)

    k_zero<<<(N_NODES + 255) / 256, 256, 0, stream>>>(deg, sums2, sums3, pooled);
    k_count<<<EB, 256, 0, stream>>>(e_dst, deg);
    k_scan1<<<NSB, SB, 0, stream>>>(deg, bsum);
    k_scan2<<<1, 64, 0, stream>>>(bsum, boff);
    k_scan3<<<NSB, SB, 0, stream>>>(deg, boff, off, cursor, invd);
    k_scatter<<<EB, 256, 0, stream>>>(e_src, e_dst, cursor, csr_src);

    // Layer 1 (no BN on input)
    k_gemm<false><<<GB, 256, 0, stream>>>(x0, Ws1, Wn1, b1, nullptr, nullptr,
                                          bufXS, (unsigned short*)bufXN);
    k_agg<false><<<AB, 256, 0, stream>>>(bufXS, bufXN, off, csr_src, invd, nullptr, bufH, nullptr);

    // BN2 stats + Layer 2
    k_stats<<<240, 256, 0, stream>>>(bufH, sums2);
    k_bnfin<<<1, 64, 0, stream>>>(sums2, g2, be2, a2, c2);
    k_gemm<true><<<GB, 256, 0, stream>>>(bufH, Ws2, Wn2, b2, a2, c2,
                                         bufXS, (unsigned short*)bufXN);
    k_agg<false><<<AB, 256, 0, stream>>>(bufXS, bufXN, off, csr_src, invd, nullptr, bufH, nullptr);

    // BN3 stats + Layer 3 (fused pooling)
    k_stats<<<240, 256, 0, stream>>>(bufH, sums3);
    k_bnfin<<<1, 64, 0, stream>>>(sums3, g3, be3, a3, c3);
    k_gemm<true><<<GB, 256, 0, stream>>>(bufH, Ws3, Wn3, b3, a3, c3,
                                         bufXS, (unsigned short*)bufXN);
    k_agg<true><<<AB, 256, 0, stream>>>(bufXS, bufXN, off, csr_src, invd, gind, bufH, pooled);

    // MLP head
    k_mlp<<<NUM_GRAPHS, 128, 0, stream>>>(pooled, fcW1, fcb1, fcW2, fcb2, fcW3, fcb3, out);
}

// Round 7
// 345.744 us; speedup vs baseline: 1.9096x; 1.1341x over previous
//
#include <hip/hip_runtime.h>

#define N_NODES   50000
#define N_EDGES   800000
#define DIM       64
#define NUM_GRAPHS 512
#define EPS       1e-5f

#define SB   1024
#define NSB  ((N_NODES + SB - 1) / SB)   // 49 scan blocks

// ---------------------------------------------------------------- zero init
__global__ void k_zero(int* __restrict__ deg, float* __restrict__ sums2,
                       float* __restrict__ sums3, float* __restrict__ pooled) {
    int i = blockIdx.x * 256 + threadIdx.x;
    if (i < N_NODES) deg[i] = 0;
    if (i < 128) { sums2[i] = 0.f; sums3[i] = 0.f; }
    if (i < NUM_GRAPHS * DIM) pooled[i] = 0.f;
}

// ---------------------------------------------------------------- degree count
__global__ void k_count(const int* __restrict__ dst, int* __restrict__ deg) {
    int i = blockIdx.x * 256 + threadIdx.x;
    if (i < N_EDGES) atomicAdd(&deg[dst[i]], 1);
}

// ---------------------------------------------------------------- scan phase 1: per-block sums
__global__ void __launch_bounds__(1024)
k_scan1(const int* __restrict__ deg, int* __restrict__ bsum) {
    __shared__ int red[16];
    int t = threadIdx.x;
    int i = blockIdx.x * SB + t;
    int v = (i < N_NODES) ? deg[i] : 0;
#pragma unroll
    for (int d = 32; d; d >>= 1) v += __shfl_down(v, d, 64);
    if ((t & 63) == 0) red[t >> 6] = v;
    __syncthreads();
    if (t < 16) {
        int s = red[t];
#pragma unroll
        for (int d = 8; d; d >>= 1) s += __shfl_down(s, d, 16);
        if (t == 0) bsum[blockIdx.x] = s;
    }
}

// ---------------------------------------------------------------- scan phase 2: scan of 49 block sums (1 wave)
__global__ void k_scan2(const int* __restrict__ bsum, int* __restrict__ boff) {
    int t = threadIdx.x;   // 64 threads
    int v = (t < NSB) ? bsum[t] : 0;
    int orig = v;
#pragma unroll
    for (int d = 1; d < 64; d <<= 1) {
        int u = __shfl_up(v, d, 64);
        if (t >= d) v += u;
    }
    if (t < NSB) boff[t] = v - orig;   // exclusive prefix
}

// ---------------------------------------------------------------- scan phase 3: full exclusive scan, write off/cursor/invd
__global__ void __launch_bounds__(1024)
k_scan3(const int* __restrict__ deg, const int* __restrict__ boff,
        int* __restrict__ off, int* __restrict__ cursor, float* __restrict__ invd) {
    __shared__ int wsum[16];
    int t = threadIdx.x, lane = t & 63, w = t >> 6;
    int i = blockIdx.x * SB + t;
    int d = (i < N_NODES) ? deg[i] : 0;
    int v = d;
#pragma unroll
    for (int s = 1; s < 64; s <<= 1) {
        int u = __shfl_up(v, s, 64);
        if (lane >= s) v += u;
    }
    if (lane == 63) wsum[w] = v;
    __syncthreads();
    if (t < 16) {
        int x = wsum[t];
#pragma unroll
        for (int s = 1; s < 16; s <<= 1) {
            int u = __shfl_up(x, s, 16);
            if (t >= s) x += u;
        }
        wsum[t] = x;   // inclusive across waves (lockstep within wave 0)
    }
    __syncthreads();
    if (i < N_NODES) {
        int ex = boff[blockIdx.x] + ((w > 0) ? wsum[w - 1] : 0) + v - d;
        off[i] = ex;
        cursor[i] = ex;
        invd[i] = 1.0f / (float)max(d, 1);
        if (i == N_NODES - 1) off[N_NODES] = ex + d;
    }
}

// ---------------------------------------------------------------- CSR scatter (direct)
__global__ void k_scatter(const int* __restrict__ src, const int* __restrict__ dst,
                          int* __restrict__ cursor, int* __restrict__ csr_src) {
    int i = blockIdx.x * 256 + threadIdx.x;
    if (i < N_EDGES) {
        int p = atomicAdd(&cursor[dst[i]], 1);
        csr_src[p] = src[i];
    }
}

// ---------------------------------------------------------------- fp32 -> bf16 RNE
__device__ inline unsigned short f2bf(float f) {
    unsigned u = __float_as_uint(f);
    return (unsigned short)((u + 0x7FFFu + ((u >> 16) & 1u)) >> 16);
}

// ---------------------------------------------------------------- dual GEMM, weights in registers
// xs = BN(x)@Ws + b (fp32) ; xnh16 = bf16 BN(x)@Wn (ushort/lane, coalesced).
#define GR 32   // rows per block
template<bool BN>
__global__ void __launch_bounds__(256)
k_gemm(const float* __restrict__ x, const float* __restrict__ Ws,
       const float* __restrict__ Wn, const float* __restrict__ bias,
       const float* __restrict__ bn_a, const float* __restrict__ bn_c,
       float* __restrict__ xs, unsigned short* __restrict__ xnh16) {
    __shared__ float sX[GR][DIM];
    int tid = threadIdx.x;
    int lane = tid & 63, w = tid >> 6;

    // per-thread column of each weight matrix, fully unrolled -> registers
    float wsr[DIM], wnr[DIM];
#pragma unroll
    for (int k = 0; k < DIM; ++k) {
        wsr[k] = Ws[k * DIM + lane];
        wnr[k] = Wn[k * DIM + lane];
    }
    float bv = bias[lane];
    float aL = 1.f, cL = 0.f;
    if constexpr (BN) { aL = bn_a[lane]; cL = bn_c[lane]; }

    int rowBase = blockIdx.x * GR;
#pragma unroll
    for (int r = 0; r < GR / 4; ++r) {
        int row = r * 4 + w;
        int gr = rowBase + row;
        float v = (gr < N_NODES) ? x[gr * DIM + lane] : 0.f;
        sX[row][lane] = fmaf(v, aL, cL);
    }
    __syncthreads();

    // wave w computes rows [w*8, w*8+8)
#pragma unroll
    for (int r = 0; r < 8; ++r) {
        int row = w * 8 + r;
        float s = bv, n = 0.f;
#pragma unroll
        for (int kg = 0; kg < DIM / 4; ++kg) {
            float4 xv = *reinterpret_cast<const float4*>(&sX[row][kg * 4]);
            s = fmaf(xv.x, wsr[kg * 4 + 0], s); n = fmaf(xv.x, wnr[kg * 4 + 0], n);
            s = fmaf(xv.y, wsr[kg * 4 + 1], s); n = fmaf(xv.y, wnr[kg * 4 + 1], n);
            s = fmaf(xv.z, wsr[kg * 4 + 2], s); n = fmaf(xv.z, wnr[kg * 4 + 2], n);
            s = fmaf(xv.w, wsr[kg * 4 + 3], s); n = fmaf(xv.w, wnr[kg * 4 + 3], n);
        }
        int grow = rowBase + row;
        if (grow < N_NODES) {
            xs[grow * DIM + lane] = s;
            xnh16[grow * DIM + lane] = f2bf(n);   // 64x2B = one 128B coalesced store
        }
    }
}

// ---------------------------------------------------------------- aggregate: h = relu(xs + inv_deg * sum_{src} xn[src])
// xn is bf16 (64 ushort/row = 128B, read as 32 words). Wave = 1 dst row;
// two 32-lane halves process alternating edges (4-deep unrolled for MLP);
// combine via shfl_xor(32).
template<bool POOL>
__global__ void __launch_bounds__(256)
k_agg(const float* __restrict__ xs, const unsigned* __restrict__ xnh,
      const int* __restrict__ off, const int* __restrict__ csr_src,
      const float* __restrict__ inv_deg, const int* __restrict__ gind,
      float* __restrict__ h, float* __restrict__ pooled) {
    int tid = threadIdx.x;
    int w = tid >> 6;            // wave index = row within block
    int lane = tid & 63;
    int hw = lane >> 5;          // which parity of edges this half handles
    int p = lane & 31;           // channel pair index
    int row = blockIdx.x * 4 + w;
    if (row >= N_NODES) return;
    int jb = off[row], je = off[row + 1];
    float ax = 0.f, ay = 0.f;
    int j = jb + hw;
    // 4-deep unroll (stride 2 per half) -> 4 independent gathers in flight
    for (; j + 6 < je; j += 8) {
        int s0 = csr_src[j];
        int s1 = csr_src[j + 2];
        int s2 = csr_src[j + 4];
        int s3 = csr_src[j + 6];
        unsigned w0 = xnh[s0 * 32 + p];
        unsigned w1 = xnh[s1 * 32 + p];
        unsigned w2 = xnh[s2 * 32 + p];
        unsigned w3 = xnh[s3 * 32 + p];
        ax += (__uint_as_float(w0 << 16) + __uint_as_float(w1 << 16))
            + (__uint_as_float(w2 << 16) + __uint_as_float(w3 << 16));
        ay += (__uint_as_float(w0 & 0xFFFF0000u) + __uint_as_float(w1 & 0xFFFF0000u))
            + (__uint_as_float(w2 & 0xFFFF0000u) + __uint_as_float(w3 & 0xFFFF0000u));
    }
    for (; j < je; j += 2) {
        int s = csr_src[j];
        unsigned wd = xnh[s * 32 + p];
        ax += __uint_as_float(wd << 16);
        ay += __uint_as_float(wd & 0xFFFF0000u);
    }
    ax += __shfl_xor(ax, 32, 64);
    ay += __shfl_xor(ay, 32, 64);
    if (hw == 0) {
        float id = inv_deg[row];
        float2 xv = *reinterpret_cast<const float2*>(&xs[row * DIM + 2 * p]);
        float vx = fmaxf(fmaf(ax, id, xv.x), 0.f);
        float vy = fmaxf(fmaf(ay, id, xv.y), 0.f);
        *reinterpret_cast<float2*>(&h[row * DIM + 2 * p]) = make_float2(vx, vy);
        if constexpr (POOL) {
            int g = gind[row];
            atomicAdd(&pooled[g * DIM + 2 * p], vx);
            atomicAdd(&pooled[g * DIM + 2 * p + 1], vy);
        }
    }
}

// ---------------------------------------------------------------- BN stats (sum, sumsq per channel)
__global__ void __launch_bounds__(256)
k_stats(const float* __restrict__ h, float* __restrict__ sums) {
    int lane = threadIdx.x & 63, w = threadIdx.x >> 6;
    float s = 0.f, q = 0.f;
    for (int r = blockIdx.x * 4 + w; r < N_NODES; r += gridDim.x * 4) {
        float v = h[r * DIM + lane];
        s += v;
        q = fmaf(v, v, q);
    }
    __shared__ float sS[4][DIM], sQ[4][DIM];
    sS[w][lane] = s; sQ[w][lane] = q;
    __syncthreads();
    if (w == 0) {
        float ts = sS[0][lane] + sS[1][lane] + sS[2][lane] + sS[3][lane];
        float tq = sQ[0][lane] + sQ[1][lane] + sQ[2][lane] + sQ[3][lane];
        atomicAdd(&sums[lane], ts);
        atomicAdd(&sums[DIM + lane], tq);
    }
}

// ---------------------------------------------------------------- BN finalize: a = g*rsqrt(var+eps), c = be - mean*a
__global__ void k_bnfin(const float* __restrict__ sums, const float* __restrict__ g,
                        const float* __restrict__ be, float* __restrict__ a,
                        float* __restrict__ c) {
    int t = threadIdx.x;  // 64 threads
    float m = sums[t] * (1.0f / N_NODES);
    float q = sums[DIM + t] * (1.0f / N_NODES);
    float v = q - m * m;
    float inv = 1.0f / sqrtf(v + EPS);
    float av = g[t] * inv;
    a[t] = av;
    c[t] = be[t] - m * av;
}

// ---------------------------------------------------------------- MLP head (one block per graph)
__global__ void __launch_bounds__(128)
k_mlp(const float* __restrict__ pooled,
      const float* __restrict__ W1, const float* __restrict__ b1,
      const float* __restrict__ W2, const float* __restrict__ b2,
      const float* __restrict__ W3, const float* __restrict__ b3,
      float* __restrict__ out) {
    __shared__ float sp[64], s1[128], s2[64];
    int g = blockIdx.x, t = threadIdx.x;
    if (t < 64) sp[t] = pooled[g * 64 + t];
    __syncthreads();
    {
        float acc = b1[t];
#pragma unroll
        for (int k = 0; k < 64; ++k) acc = fmaf(sp[k], W1[k * 128 + t], acc);
        s1[t] = fmaxf(acc, 0.f);
    }
    __syncthreads();
    if (t < 64) {
        float acc = b2[t];
#pragma unroll
        for (int k = 0; k < 128; ++k) acc = fmaf(s1[k], W2[k * 64 + t], acc);
        s2[t] = fmaxf(acc, 0.f);
    }
    __syncthreads();
    if (t < 10) {
        float acc = b3[t];
#pragma unroll
        for (int k = 0; k < 64; ++k) acc = fmaf(s2[k], W3[k * 10 + t], acc);
        out[g * 10 + t] = acc;
    }
}

// ---------------------------------------------------------------- launch
extern "C" void kernel_launch(void* const* d_in, const int* in_sizes, int n_in,
                              void* d_out, int out_size, void* d_ws, size_t ws_size,
                              hipStream_t stream) {
    const float* x0   = (const float*)d_in[0];
    const int* e_src  = (const int*)d_in[1];
    const int* e_dst  = (const int*)d_in[2];
    const int* gind   = (const int*)d_in[3];
    // d_in[4] = labels (unused)
    const float* Ws1 = (const float*)d_in[5],  *Wn1 = (const float*)d_in[6],  *b1 = (const float*)d_in[7];
    const float* Ws2 = (const float*)d_in[8],  *Wn2 = (const float*)d_in[9],  *b2 = (const float*)d_in[10];
    const float* Ws3 = (const float*)d_in[11], *Wn3 = (const float*)d_in[12], *b3 = (const float*)d_in[13];
    const float* g2  = (const float*)d_in[14], *be2 = (const float*)d_in[15];
    const float* g3  = (const float*)d_in[16], *be3 = (const float*)d_in[17];
    const float* fcW1 = (const float*)d_in[18], *fcb1 = (const float*)d_in[19];
    const float* fcW2 = (const float*)d_in[20], *fcb2 = (const float*)d_in[21];
    const float* fcW3 = (const float*)d_in[22], *fcb3 = (const float*)d_in[23];
    float* out = (float*)d_out;

    char* p = (char*)d_ws;
    auto carve = [&](size_t bytes) { void* r = (void*)p; p += (bytes + 255) & ~(size_t)255; return r; };
    int*   deg     = (int*)  carve(N_NODES * 4);
    int*   off     = (int*)  carve((N_NODES + 1) * 4);
    int*   cursor  = (int*)  carve(N_NODES * 4);
    int*   csr_src = (int*)  carve(N_EDGES * 4);
    float* invd    = (float*)carve(N_NODES * 4);
    int*   bsum    = (int*)  carve(NSB * 4);
    int*   boff    = (int*)  carve((NSB + 1) * 4);
    float* sums2   = (float*)carve(128 * 4);
    float* sums3   = (float*)carve(128 * 4);
    float* a2      = (float*)carve(64 * 4);
    float* c2      = (float*)carve(64 * 4);
    float* a3      = (float*)carve(64 * 4);
    float* c3      = (float*)carve(64 * 4);
    float* pooled  = (float*)carve(NUM_GRAPHS * DIM * 4);
    float* bufH    = (float*)carve((size_t)N_NODES * DIM * 4);
    float* bufXS   = (float*)carve((size_t)N_NODES * DIM * 4);
    unsigned* bufXN = (unsigned*)carve((size_t)N_NODES * 32 * 4);   // bf16-packed

    const int EB = (N_EDGES + 255) / 256;           // 3125
    const int GB = (N_NODES + GR - 1) / GR;         // 1563 (gemm: 32 rows/block)
    const int AB = (N_NODES + 3) / 4;               // 12500 (agg: 4 rows/block)

    k_zero<<<(N_NODES + 255) / 256, 256, 0, stream>>>(deg, sums2, sums3, pooled);
    k_count<<<EB, 256, 0, stream>>>(e_dst, deg);
    k_scan1<<<NSB, SB, 0, stream>>>(deg, bsum);
    k_scan2<<<1, 64, 0, stream>>>(bsum, boff);
    k_scan3<<<NSB, SB, 0, stream>>>(deg, boff, off, cursor, invd);
    k_scatter<<<EB, 256, 0, stream>>>(e_src, e_dst, cursor, csr_src);

    // Layer 1 (no BN on input)
    k_gemm<false><<<GB, 256, 0, stream>>>(x0, Ws1, Wn1, b1, nullptr, nullptr,
                                          bufXS, (unsigned short*)bufXN);
    k_agg<false><<<AB, 256, 0, stream>>>(bufXS, bufXN, off, csr_src, invd, nullptr, bufH, nullptr);

    // BN2 stats + Layer 2
    k_stats<<<240, 256, 0, stream>>>(bufH, sums2);
    k_bnfin<<<1, 64, 0, stream>>>(sums2, g2, be2, a2, c2);
    k_gemm<true><<<GB, 256, 0, stream>>>(bufH, Ws2, Wn2, b2, a2, c2,
                                         bufXS, (unsigned short*)bufXN);
    k_agg<false><<<AB, 256, 0, stream>>>(bufXS, bufXN, off, csr_src, invd, nullptr, bufH, nullptr);

    // BN3 stats + Layer 3 (fused pooling)
    k_stats<<<240, 256, 0, stream>>>(bufH, sums3);
    k_bnfin<<<1, 64, 0, stream>>>(sums3, g3, be3, a3, c3);
    k_gemm<true><<<GB, 256, 0, stream>>>(bufH, Ws3, Wn3, b3, a3, c3,
                                         bufXS, (unsigned short*)bufXN);
    k_agg<true><<<AB, 256, 0, stream>>>(bufXS, bufXN, off, csr_src, invd, gind, bufH, pooled);

    // MLP head
    k_mlp<<<NUM_GRAPHS, 128, 0, stream>>>(pooled, fcW1, fcb1, fcW2, fcb2, fcW3, fcb3, out);
}

// Round 8
// 339.409 us; speedup vs baseline: 1.9452x; 1.0187x over previous
//
#include <hip/hip_runtime.h>

#define N_NODES   50000
#define N_EDGES   800000
#define DIM       64
#define NUM_GRAPHS 512
#define EPS       1e-5f

#define SB   1024
#define NSB  ((N_NODES + SB - 1) / SB)   // 49 scan blocks

// ---------------------------------------------------------------- zero init
__global__ void k_zero(int* __restrict__ deg, float* __restrict__ sums2,
                       float* __restrict__ sums3, float* __restrict__ pooled) {
    int i = blockIdx.x * 256 + threadIdx.x;
    if (i < N_NODES) deg[i] = 0;
    if (i < 128) { sums2[i] = 0.f; sums3[i] = 0.f; }
    if (i < NUM_GRAPHS * DIM) pooled[i] = 0.f;
}

// ---------------------------------------------------------------- degree count
__global__ void k_count(const int* __restrict__ dst, int* __restrict__ deg) {
    int i = blockIdx.x * 256 + threadIdx.x;
    if (i < N_EDGES) atomicAdd(&deg[dst[i]], 1);
}

// ---------------------------------------------------------------- scan phase 1: per-block sums
__global__ void __launch_bounds__(1024)
k_scan1(const int* __restrict__ deg, int* __restrict__ bsum) {
    __shared__ int red[16];
    int t = threadIdx.x;
    int i = blockIdx.x * SB + t;
    int v = (i < N_NODES) ? deg[i] : 0;
#pragma unroll
    for (int d = 32; d; d >>= 1) v += __shfl_down(v, d, 64);
    if ((t & 63) == 0) red[t >> 6] = v;
    __syncthreads();
    if (t < 16) {
        int s = red[t];
#pragma unroll
        for (int d = 8; d; d >>= 1) s += __shfl_down(s, d, 16);
        if (t == 0) bsum[blockIdx.x] = s;
    }
}

// ---------------------------------------------------------------- scan phase 2: scan of 49 block sums (1 wave)
__global__ void k_scan2(const int* __restrict__ bsum, int* __restrict__ boff) {
    int t = threadIdx.x;   // 64 threads
    int v = (t < NSB) ? bsum[t] : 0;
    int orig = v;
#pragma unroll
    for (int d = 1; d < 64; d <<= 1) {
        int u = __shfl_up(v, d, 64);
        if (t >= d) v += u;
    }
    if (t < NSB) boff[t] = v - orig;   // exclusive prefix
}

// ---------------------------------------------------------------- scan phase 3: full exclusive scan, write off/cursor/invd
__global__ void __launch_bounds__(1024)
k_scan3(const int* __restrict__ deg, const int* __restrict__ boff,
        int* __restrict__ off, int* __restrict__ cursor, float* __restrict__ invd) {
    __shared__ int wsum[16];
    int t = threadIdx.x, lane = t & 63, w = t >> 6;
    int i = blockIdx.x * SB + t;
    int d = (i < N_NODES) ? deg[i] : 0;
    int v = d;
#pragma unroll
    for (int s = 1; s < 64; s <<= 1) {
        int u = __shfl_up(v, s, 64);
        if (lane >= s) v += u;
    }
    if (lane == 63) wsum[w] = v;
    __syncthreads();
    if (t < 16) {
        int x = wsum[t];
#pragma unroll
        for (int s = 1; s < 16; s <<= 1) {
            int u = __shfl_up(x, s, 16);
            if (t >= s) x += u;
        }
        wsum[t] = x;   // inclusive across waves (lockstep within wave 0)
    }
    __syncthreads();
    if (i < N_NODES) {
        int ex = boff[blockIdx.x] + ((w > 0) ? wsum[w - 1] : 0) + v - d;
        off[i] = ex;
        cursor[i] = ex;
        invd[i] = 1.0f / (float)max(d, 1);
        if (i == N_NODES - 1) off[N_NODES] = ex + d;
    }
}

// ---------------------------------------------------------------- CSR scatter (direct)
__global__ void k_scatter(const int* __restrict__ src, const int* __restrict__ dst,
                          int* __restrict__ cursor, int* __restrict__ csr_src) {
    int i = blockIdx.x * 256 + threadIdx.x;
    if (i < N_EDGES) {
        int p = atomicAdd(&cursor[dst[i]], 1);
        csr_src[p] = src[i];
    }
}

// ---------------------------------------------------------------- fp32 -> bf16 RNE
__device__ inline unsigned short f2bf(float f) {
    unsigned u = __float_as_uint(f);
    return (unsigned short)((u + 0x7FFFu + ((u >> 16) & 1u)) >> 16);
}

// ---------------------------------------------------------------- dual GEMM, weights in registers
// xs = BN(x)@Ws + b (fp32) ; xnh16 = bf16 BN(x)@Wn (ushort/lane, coalesced).
#define GR 32   // rows per block
template<bool BN>
__global__ void __launch_bounds__(256)
k_gemm(const float* __restrict__ x, const float* __restrict__ Ws,
       const float* __restrict__ Wn, const float* __restrict__ bias,
       const float* __restrict__ bn_a, const float* __restrict__ bn_c,
       float* __restrict__ xs, unsigned short* __restrict__ xnh16) {
    __shared__ float sX[GR][DIM];
    int tid = threadIdx.x;
    int lane = tid & 63, w = tid >> 6;

    // per-thread column of each weight matrix, fully unrolled -> registers
    float wsr[DIM], wnr[DIM];
#pragma unroll
    for (int k = 0; k < DIM; ++k) {
        wsr[k] = Ws[k * DIM + lane];
        wnr[k] = Wn[k * DIM + lane];
    }
    float bv = bias[lane];
    float aL = 1.f, cL = 0.f;
    if constexpr (BN) { aL = bn_a[lane]; cL = bn_c[lane]; }

    int rowBase = blockIdx.x * GR;
#pragma unroll
    for (int r = 0; r < GR / 4; ++r) {
        int row = r * 4 + w;
        int gr = rowBase + row;
        float v = (gr < N_NODES) ? x[gr * DIM + lane] : 0.f;
        sX[row][lane] = fmaf(v, aL, cL);
    }
    __syncthreads();

    // wave w computes rows [w*8, w*8+8)
#pragma unroll
    for (int r = 0; r < 8; ++r) {
        int row = w * 8 + r;
        float s = bv, n = 0.f;
#pragma unroll
        for (int kg = 0; kg < DIM / 4; ++kg) {
            float4 xv = *reinterpret_cast<const float4*>(&sX[row][kg * 4]);
            s = fmaf(xv.x, wsr[kg * 4 + 0], s); n = fmaf(xv.x, wnr[kg * 4 + 0], n);
            s = fmaf(xv.y, wsr[kg * 4 + 1], s); n = fmaf(xv.y, wnr[kg * 4 + 1], n);
            s = fmaf(xv.z, wsr[kg * 4 + 2], s); n = fmaf(xv.z, wnr[kg * 4 + 2], n);
            s = fmaf(xv.w, wsr[kg * 4 + 3], s); n = fmaf(xv.w, wnr[kg * 4 + 3], n);
        }
        int grow = rowBase + row;
        if (grow < N_NODES) {
            xs[grow * DIM + lane] = s;
            xnh16[grow * DIM + lane] = f2bf(n);   // 64x2B = one 128B coalesced store
        }
    }
}

// ---------------------------------------------------------------- aggregate: h = relu(xs + inv_deg * sum_{src} xn[src])
// xn is bf16 (32 words/row = 128B). Each 32-lane HALF-WAVE owns 2 consecutive
// rows; their 4-deep unrolled gather chains run interleaved (8 outstanding
// gathers per half, 16 per wave). Tail slots clamp to row 0 (L1-hot).
template<bool POOL>
__global__ void __launch_bounds__(256)
k_agg(const float* __restrict__ xs, const unsigned* __restrict__ xnh,
      const int* __restrict__ off, const int* __restrict__ csr_src,
      const float* __restrict__ inv_deg, const int* __restrict__ gind,
      float* __restrict__ h, float* __restrict__ pooled) {
    int tid = threadIdx.x;
    int w = tid >> 6;            // wave index within block
    int lane = tid & 63;
    int hw = lane >> 5;          // half-wave id
    int p = lane & 31;           // channel pair index
    int half_id = blockIdx.x * 8 + w * 2 + hw;   // 8 halves per block
    int rA = half_id * 2;                         // 16 rows per block; 50000=3125*16
    int rB = rA + 1;
    int jA = off[rA], jeA = off[rA + 1];
    int jB = jeA,     jeB = off[rB + 1];
    float axA = 0.f, ayA = 0.f, axB = 0.f, ayB = 0.f;

    while (jA < jeA || jB < jeB) {
#pragma unroll
        for (int k = 0; k < 4; ++k) {
            int iA = jA + k, iB = jB + k;
            bool vA = iA < jeA, vB = iB < jeB;
            int sA = csr_src[min(iA, N_EDGES - 1)];
            int sB = csr_src[min(iB, N_EDGES - 1)];
            sA = vA ? sA : 0;                      // tail -> row 0 (hot)
            sB = vB ? sB : 0;
            unsigned wA = xnh[sA * 32 + p];
            unsigned wB = xnh[sB * 32 + p];
            axA += vA ? __uint_as_float(wA << 16) : 0.f;
            ayA += vA ? __uint_as_float(wA & 0xFFFF0000u) : 0.f;
            axB += vB ? __uint_as_float(wB << 16) : 0.f;
            ayB += vB ? __uint_as_float(wB & 0xFFFF0000u) : 0.f;
        }
        jA += 4; jB += 4;
    }

    float idA = inv_deg[rA], idB = inv_deg[rB];
    float2 xvA = *reinterpret_cast<const float2*>(&xs[rA * DIM + 2 * p]);
    float2 xvB = *reinterpret_cast<const float2*>(&xs[rB * DIM + 2 * p]);
    float vxA = fmaxf(fmaf(axA, idA, xvA.x), 0.f);
    float vyA = fmaxf(fmaf(ayA, idA, xvA.y), 0.f);
    float vxB = fmaxf(fmaf(axB, idB, xvB.x), 0.f);
    float vyB = fmaxf(fmaf(ayB, idB, xvB.y), 0.f);
    *reinterpret_cast<float2*>(&h[rA * DIM + 2 * p]) = make_float2(vxA, vyA);
    *reinterpret_cast<float2*>(&h[rB * DIM + 2 * p]) = make_float2(vxB, vyB);
    if constexpr (POOL) {
        int gA = gind[rA], gB = gind[rB];
        atomicAdd(&pooled[gA * DIM + 2 * p], vxA);
        atomicAdd(&pooled[gA * DIM + 2 * p + 1], vyA);
        atomicAdd(&pooled[gB * DIM + 2 * p], vxB);
        atomicAdd(&pooled[gB * DIM + 2 * p + 1], vyB);
    }
}

// ---------------------------------------------------------------- BN stats (sum, sumsq per channel)
__global__ void __launch_bounds__(256)
k_stats(const float* __restrict__ h, float* __restrict__ sums) {
    int lane = threadIdx.x & 63, w = threadIdx.x >> 6;
    float s = 0.f, q = 0.f;
    for (int r = blockIdx.x * 4 + w; r < N_NODES; r += gridDim.x * 4) {
        float v = h[r * DIM + lane];
        s += v;
        q = fmaf(v, v, q);
    }
    __shared__ float sS[4][DIM], sQ[4][DIM];
    sS[w][lane] = s; sQ[w][lane] = q;
    __syncthreads();
    if (w == 0) {
        float ts = sS[0][lane] + sS[1][lane] + sS[2][lane] + sS[3][lane];
        float tq = sQ[0][lane] + sQ[1][lane] + sQ[2][lane] + sQ[3][lane];
        atomicAdd(&sums[lane], ts);
        atomicAdd(&sums[DIM + lane], tq);
    }
}

// ---------------------------------------------------------------- BN finalize: a = g*rsqrt(var+eps), c = be - mean*a
__global__ void k_bnfin(const float* __restrict__ sums, const float* __restrict__ g,
                        const float* __restrict__ be, float* __restrict__ a,
                        float* __restrict__ c) {
    int t = threadIdx.x;  // 64 threads
    float m = sums[t] * (1.0f / N_NODES);
    float q = sums[DIM + t] * (1.0f / N_NODES);
    float v = q - m * m;
    float inv = 1.0f / sqrtf(v + EPS);
    float av = g[t] * inv;
    a[t] = av;
    c[t] = be[t] - m * av;
}

// ---------------------------------------------------------------- MLP head (one block per graph)
__global__ void __launch_bounds__(128)
k_mlp(const float* __restrict__ pooled,
      const float* __restrict__ W1, const float* __restrict__ b1,
      const float* __restrict__ W2, const float* __restrict__ b2,
      const float* __restrict__ W3, const float* __restrict__ b3,
      float* __restrict__ out) {
    __shared__ float sp[64], s1[128], s2[64];
    int g = blockIdx.x, t = threadIdx.x;
    if (t < 64) sp[t] = pooled[g * 64 + t];
    __syncthreads();
    {
        float acc = b1[t];
#pragma unroll
        for (int k = 0; k < 64; ++k) acc = fmaf(sp[k], W1[k * 128 + t], acc);
        s1[t] = fmaxf(acc, 0.f);
    }
    __syncthreads();
    if (t < 64) {
        float acc = b2[t];
#pragma unroll
        for (int k = 0; k < 128; ++k) acc = fmaf(s1[k], W2[k * 64 + t], acc);
        s2[t] = fmaxf(acc, 0.f);
    }
    __syncthreads();
    if (t < 10) {
        float acc = b3[t];
#pragma unroll
        for (int k = 0; k < 64; ++k) acc = fmaf(s2[k], W3[k * 10 + t], acc);
        out[g * 10 + t] = acc;
    }
}

// ---------------------------------------------------------------- launch
extern "C" void kernel_launch(void* const* d_in, const int* in_sizes, int n_in,
                              void* d_out, int out_size, void* d_ws, size_t ws_size,
                              hipStream_t stream) {
    const float* x0   = (const float*)d_in[0];
    const int* e_src  = (const int*)d_in[1];
    const int* e_dst  = (const int*)d_in[2];
    const int* gind   = (const int*)d_in[3];
    // d_in[4] = labels (unused)
    const float* Ws1 = (const float*)d_in[5],  *Wn1 = (const float*)d_in[6],  *b1 = (const float*)d_in[7];
    const float* Ws2 = (const float*)d_in[8],  *Wn2 = (const float*)d_in[9],  *b2 = (const float*)d_in[10];
    const float* Ws3 = (const float*)d_in[11], *Wn3 = (const float*)d_in[12], *b3 = (const float*)d_in[13];
    const float* g2  = (const float*)d_in[14], *be2 = (const float*)d_in[15];
    const float* g3  = (const float*)d_in[16], *be3 = (const float*)d_in[17];
    const float* fcW1 = (const float*)d_in[18], *fcb1 = (const float*)d_in[19];
    const float* fcW2 = (const float*)d_in[20], *fcb2 = (const float*)d_in[21];
    const float* fcW3 = (const float*)d_in[22], *fcb3 = (const float*)d_in[23];
    float* out = (float*)d_out;

    char* p = (char*)d_ws;
    auto carve = [&](size_t bytes) { void* r = (void*)p; p += (bytes + 255) & ~(size_t)255; return r; };
    int*   deg     = (int*)  carve(N_NODES * 4);
    int*   off     = (int*)  carve((N_NODES + 1) * 4);
    int*   cursor  = (int*)  carve(N_NODES * 4);
    int*   csr_src = (int*)  carve(N_EDGES * 4);
    float* invd    = (float*)carve(N_NODES * 4);
    int*   bsum    = (int*)  carve(NSB * 4);
    int*   boff    = (int*)  carve((NSB + 1) * 4);
    float* sums2   = (float*)carve(128 * 4);
    float* sums3   = (float*)carve(128 * 4);
    float* a2      = (float*)carve(64 * 4);
    float* c2      = (float*)carve(64 * 4);
    float* a3      = (float*)carve(64 * 4);
    float* c3      = (float*)carve(64 * 4);
    float* pooled  = (float*)carve(NUM_GRAPHS * DIM * 4);
    float* bufH    = (float*)carve((size_t)N_NODES * DIM * 4);
    float* bufXS   = (float*)carve((size_t)N_NODES * DIM * 4);
    unsigned* bufXN = (unsigned*)carve((size_t)N_NODES * 32 * 4);   // bf16-packed

    const int EB = (N_EDGES + 255) / 256;           // 3125
    const int GB = (N_NODES + GR - 1) / GR;         // 1563 (gemm: 32 rows/block)
    const int AB2 = N_NODES / 16;                   // 3125 (agg: 16 rows/block)

    k_zero<<<(N_NODES + 255) / 256, 256, 0, stream>>>(deg, sums2, sums3, pooled);
    k_count<<<EB, 256, 0, stream>>>(e_dst, deg);
    k_scan1<<<NSB, SB, 0, stream>>>(deg, bsum);
    k_scan2<<<1, 64, 0, stream>>>(bsum, boff);
    k_scan3<<<NSB, SB, 0, stream>>>(deg, boff, off, cursor, invd);
    k_scatter<<<EB, 256, 0, stream>>>(e_src, e_dst, cursor, csr_src);

    // Layer 1 (no BN on input)
    k_gemm<false><<<GB, 256, 0, stream>>>(x0, Ws1, Wn1, b1, nullptr, nullptr,
                                          bufXS, (unsigned short*)bufXN);
    k_agg<false><<<AB2, 256, 0, stream>>>(bufXS, bufXN, off, csr_src, invd, nullptr, bufH, nullptr);

    // BN2 stats + Layer 2
    k_stats<<<240, 256, 0, stream>>>(bufH, sums2);
    k_bnfin<<<1, 64, 0, stream>>>(sums2, g2, be2, a2, c2);
    k_gemm<true><<<GB, 256, 0, stream>>>(bufH, Ws2, Wn2, b2, a2, c2,
                                         bufXS, (unsigned short*)bufXN);
    k_agg<false><<<AB2, 256, 0, stream>>>(bufXS, bufXN, off, csr_src, invd, nullptr, bufH, nullptr);

    // BN3 stats + Layer 3 (fused pooling)
    k_stats<<<240, 256, 0, stream>>>(bufH, sums3);
    k_bnfin<<<1, 64, 0, stream>>>(sums3, g3, be3, a3, c3);
    k_gemm<true><<<GB, 256, 0, stream>>>(bufH, Ws3, Wn3, b3, a3, c3,
                                         bufXS, (unsigned short*)bufXN);
    k_agg<true><<<AB2, 256, 0, stream>>>(bufXS, bufXN, off, csr_src, invd, gind, bufH, pooled);

    // MLP head
    k_mlp<<<NUM_GRAPHS, 128, 0, stream>>>(pooled, fcW1, fcb1, fcW2, fcb2, fcW3, fcb3, out);
}

// Round 9
// 300.909 us; speedup vs baseline: 2.1941x; 1.1279x over previous
//
#include <hip/hip_runtime.h>

#define N_NODES   50000
#define N_EDGES   800000
#define DIM       64
#define NUM_GRAPHS 512
#define EPS       1e-5f

#define SB   1024
#define NSB  ((N_NODES + SB - 1) / SB)   // 49 scan blocks

#define NBUCK ((N_NODES + 255) >> 8)     // 196 coarse buckets (256 nodes each)
#define PA_E  4096                       // edges per pass-A block
#define PA_B  ((N_EDGES + PA_E - 1) / PA_E)  // 196 pass-A blocks

// ---------------------------------------------------------------- zero init
__global__ void k_zero(int* __restrict__ deg, float* __restrict__ sums2,
                       float* __restrict__ sums3, float* __restrict__ pooled) {
    int i = blockIdx.x * 256 + threadIdx.x;
    if (i < N_NODES) deg[i] = 0;
    if (i < 128) { sums2[i] = 0.f; sums3[i] = 0.f; }
    if (i < NUM_GRAPHS * DIM) pooled[i] = 0.f;
}

// ---------------------------------------------------------------- degree count
__global__ void k_count(const int* __restrict__ dst, int* __restrict__ deg) {
    int i = blockIdx.x * 256 + threadIdx.x;
    if (i < N_EDGES) atomicAdd(&deg[dst[i]], 1);
}

// ---------------------------------------------------------------- scan phase 1: per-block sums
__global__ void __launch_bounds__(1024)
k_scan1(const int* __restrict__ deg, int* __restrict__ bsum) {
    __shared__ int red[16];
    int t = threadIdx.x;
    int i = blockIdx.x * SB + t;
    int v = (i < N_NODES) ? deg[i] : 0;
#pragma unroll
    for (int d = 32; d; d >>= 1) v += __shfl_down(v, d, 64);
    if ((t & 63) == 0) red[t >> 6] = v;
    __syncthreads();
    if (t < 16) {
        int s = red[t];
#pragma unroll
        for (int d = 8; d; d >>= 1) s += __shfl_down(s, d, 16);
        if (t == 0) bsum[blockIdx.x] = s;
    }
}

// ---------------------------------------------------------------- scan phase 2: scan of 49 block sums (1 wave)
__global__ void k_scan2(const int* __restrict__ bsum, int* __restrict__ boff) {
    int t = threadIdx.x;   // 64 threads
    int v = (t < NSB) ? bsum[t] : 0;
    int orig = v;
#pragma unroll
    for (int d = 1; d < 64; d <<= 1) {
        int u = __shfl_up(v, d, 64);
        if (t >= d) v += u;
    }
    if (t < NSB) boff[t] = v - orig;   // exclusive prefix
}

// ---------------------------------------------------------------- scan phase 3: full exclusive scan, write off/invd
__global__ void __launch_bounds__(1024)
k_scan3(const int* __restrict__ deg, const int* __restrict__ boff,
        int* __restrict__ off, float* __restrict__ invd) {
    __shared__ int wsum[16];
    int t = threadIdx.x, lane = t & 63, w = t >> 6;
    int i = blockIdx.x * SB + t;
    int d = (i < N_NODES) ? deg[i] : 0;
    int v = d;
#pragma unroll
    for (int s = 1; s < 64; s <<= 1) {
        int u = __shfl_up(v, s, 64);
        if (lane >= s) v += u;
    }
    if (lane == 63) wsum[w] = v;
    __syncthreads();
    if (t < 16) {
        int x = wsum[t];
#pragma unroll
        for (int s = 1; s < 16; s <<= 1) {
            int u = __shfl_up(x, s, 16);
            if (t >= s) x += u;
        }
        wsum[t] = x;   // inclusive across waves (lockstep within wave 0)
    }
    __syncthreads();
    if (i < N_NODES) {
        int ex = boff[blockIdx.x] + ((w > 0) ? wsum[w - 1] : 0) + v - d;
        off[i] = ex;
        invd[i] = 1.0f / (float)max(d, 1);
        if (i == N_NODES - 1) off[N_NODES] = ex + d;
    }
}

// ---------------------------------------------------------------- bucket cursor init
__global__ void k_bcinit(const int* __restrict__ off, int* __restrict__ bcur) {
    int t = blockIdx.x * 256 + threadIdx.x;
    if (t < NBUCK) bcur[t] = off[t << 8];
}

// ---------------------------------------------------------------- pass A: partition edges into coarse buckets (dense runs)
__global__ void __launch_bounds__(1024)
k_passA(const int* __restrict__ src, const int* __restrict__ dst,
        int* __restrict__ bcur, unsigned long long* __restrict__ ebuf) {
    __shared__ int hist[NBUCK];
    __shared__ int gbase[NBUCK];
    int t = threadIdx.x;
    for (int i = t; i < NBUCK; i += 1024) hist[i] = 0;
    __syncthreads();
    int e0 = blockIdx.x * PA_E;
    int s0, s1, s2, s3, d0, d1, d2, d3, l0, l1, l2, l3;
    bool v0, v1, v2, v3;
    // phase 1: load + local slot reservation via LDS histogram
    {
        int e = e0 + t;
        v0 = e < N_EDGES;
        s0 = v0 ? src[min(e, N_EDGES - 1)] : 0;
        d0 = v0 ? dst[min(e, N_EDGES - 1)] : 0;
        l0 = v0 ? atomicAdd(&hist[d0 >> 8], 1) : 0;
    }
    {
        int e = e0 + t + 1024;
        v1 = e < N_EDGES;
        s1 = v1 ? src[min(e, N_EDGES - 1)] : 0;
        d1 = v1 ? dst[min(e, N_EDGES - 1)] : 0;
        l1 = v1 ? atomicAdd(&hist[d1 >> 8], 1) : 0;
    }
    {
        int e = e0 + t + 2048;
        v2 = e < N_EDGES;
        s2 = v2 ? src[min(e, N_EDGES - 1)] : 0;
        d2 = v2 ? dst[min(e, N_EDGES - 1)] : 0;
        l2 = v2 ? atomicAdd(&hist[d2 >> 8], 1) : 0;
    }
    {
        int e = e0 + t + 3072;
        v3 = e < N_EDGES;
        s3 = v3 ? src[min(e, N_EDGES - 1)] : 0;
        d3 = v3 ? dst[min(e, N_EDGES - 1)] : 0;
        l3 = v3 ? atomicAdd(&hist[d3 >> 8], 1) : 0;
    }
    __syncthreads();
    // reserve dense global runs: one atomic per (block, bucket)
    if (t < NBUCK) {
        int h = hist[t];
        gbase[t] = h ? atomicAdd(&bcur[t], h) : 0;
    }
    __syncthreads();
    // phase 2: write packed edges into reserved runs
    if (v0) ebuf[gbase[d0 >> 8] + l0] = ((unsigned long long)d0 << 32) | (unsigned)s0;
    if (v1) ebuf[gbase[d1 >> 8] + l1] = ((unsigned long long)d1 << 32) | (unsigned)s1;
    if (v2) ebuf[gbase[d2 >> 8] + l2] = ((unsigned long long)d2 << 32) | (unsigned)s2;
    if (v3) ebuf[gbase[d3 >> 8] + l3] = ((unsigned long long)d3 << 32) | (unsigned)s3;
}

// ---------------------------------------------------------------- pass B: within-bucket final CSR scatter (L2-local stores)
__global__ void __launch_bounds__(1024)
k_passB(const unsigned long long* __restrict__ ebuf, const int* __restrict__ off,
        int* __restrict__ csr_src) {
    __shared__ int lcur[256];
    int base = blockIdx.x << 8;
    int nn = min(256, N_NODES - base);
    int t = threadIdx.x;
    if (t < nn) lcur[t] = off[base + t];
    __syncthreads();
    int js = off[base];
    int je = off[base + nn];
    for (int j = js + t; j < je; j += 1024) {
        unsigned long long pk = ebuf[j];
        int d = (int)(pk >> 32);
        int s = (int)(unsigned)pk;
        int pos = atomicAdd(&lcur[d - base], 1);
        csr_src[pos] = s;
    }
}

// ---------------------------------------------------------------- fp32 -> bf16 RNE
__device__ inline unsigned short f2bf(float f) {
    unsigned u = __float_as_uint(f);
    return (unsigned short)((u + 0x7FFFu + ((u >> 16) & 1u)) >> 16);
}

// ---------------------------------------------------------------- dual GEMM, weights in registers
// xs = BN(x)@Ws + b (fp32) ; xnh16 = bf16 BN(x)@Wn (ushort/lane, coalesced).
#define GR 32   // rows per block
template<bool BN>
__global__ void __launch_bounds__(256)
k_gemm(const float* __restrict__ x, const float* __restrict__ Ws,
       const float* __restrict__ Wn, const float* __restrict__ bias,
       const float* __restrict__ bn_a, const float* __restrict__ bn_c,
       float* __restrict__ xs, unsigned short* __restrict__ xnh16) {
    __shared__ float sX[GR][DIM];
    int tid = threadIdx.x;
    int lane = tid & 63, w = tid >> 6;

    // per-thread column of each weight matrix, fully unrolled -> registers
    float wsr[DIM], wnr[DIM];
#pragma unroll
    for (int k = 0; k < DIM; ++k) {
        wsr[k] = Ws[k * DIM + lane];
        wnr[k] = Wn[k * DIM + lane];
    }
    float bv = bias[lane];
    float aL = 1.f, cL = 0.f;
    if constexpr (BN) { aL = bn_a[lane]; cL = bn_c[lane]; }

    int rowBase = blockIdx.x * GR;
#pragma unroll
    for (int r = 0; r < GR / 4; ++r) {
        int row = r * 4 + w;
        int gr = rowBase + row;
        float v = (gr < N_NODES) ? x[gr * DIM + lane] : 0.f;
        sX[row][lane] = fmaf(v, aL, cL);
    }
    __syncthreads();

    // wave w computes rows [w*8, w*8+8)
#pragma unroll
    for (int r = 0; r < 8; ++r) {
        int row = w * 8 + r;
        float s = bv, n = 0.f;
#pragma unroll
        for (int kg = 0; kg < DIM / 4; ++kg) {
            float4 xv = *reinterpret_cast<const float4*>(&sX[row][kg * 4]);
            s = fmaf(xv.x, wsr[kg * 4 + 0], s); n = fmaf(xv.x, wnr[kg * 4 + 0], n);
            s = fmaf(xv.y, wsr[kg * 4 + 1], s); n = fmaf(xv.y, wnr[kg * 4 + 1], n);
            s = fmaf(xv.z, wsr[kg * 4 + 2], s); n = fmaf(xv.z, wnr[kg * 4 + 2], n);
            s = fmaf(xv.w, wsr[kg * 4 + 3], s); n = fmaf(xv.w, wnr[kg * 4 + 3], n);
        }
        int grow = rowBase + row;
        if (grow < N_NODES) {
            xs[grow * DIM + lane] = s;
            xnh16[grow * DIM + lane] = f2bf(n);   // 64x2B = one 128B coalesced store
        }
    }
}

// ---------------------------------------------------------------- aggregate: h = relu(xs + inv_deg * sum_{src} xn[src])
// xn is bf16 (32 words/row = 128B). Each 32-lane HALF-WAVE owns 2 consecutive
// rows; their 4-deep unrolled gather chains run interleaved (8 outstanding
// gathers per half, 16 per wave). Tail slots clamp to row 0 (L1-hot).
template<bool POOL>
__global__ void __launch_bounds__(256)
k_agg(const float* __restrict__ xs, const unsigned* __restrict__ xnh,
      const int* __restrict__ off, const int* __restrict__ csr_src,
      const float* __restrict__ inv_deg, const int* __restrict__ gind,
      float* __restrict__ h, float* __restrict__ pooled) {
    int tid = threadIdx.x;
    int w = tid >> 6;            // wave index within block
    int lane = tid & 63;
    int hw = lane >> 5;          // half-wave id
    int p = lane & 31;           // channel pair index
    int half_id = blockIdx.x * 8 + w * 2 + hw;   // 8 halves per block
    int rA = half_id * 2;                         // 16 rows per block; 50000=3125*16
    int rB = rA + 1;
    int jA = off[rA], jeA = off[rA + 1];
    int jB = jeA,     jeB = off[rB + 1];
    float axA = 0.f, ayA = 0.f, axB = 0.f, ayB = 0.f;

    while (jA < jeA || jB < jeB) {
#pragma unroll
        for (int k = 0; k < 4; ++k) {
            int iA = jA + k, iB = jB + k;
            bool vA = iA < jeA, vB = iB < jeB;
            int sA = csr_src[min(iA, N_EDGES - 1)];
            int sB = csr_src[min(iB, N_EDGES - 1)];
            sA = vA ? sA : 0;                      // tail -> row 0 (hot)
            sB = vB ? sB : 0;
            unsigned wA = xnh[sA * 32 + p];
            unsigned wB = xnh[sB * 32 + p];
            axA += vA ? __uint_as_float(wA << 16) : 0.f;
            ayA += vA ? __uint_as_float(wA & 0xFFFF0000u) : 0.f;
            axB += vB ? __uint_as_float(wB << 16) : 0.f;
            ayB += vB ? __uint_as_float(wB & 0xFFFF0000u) : 0.f;
        }
        jA += 4; jB += 4;
    }

    float idA = inv_deg[rA], idB = inv_deg[rB];
    float2 xvA = *reinterpret_cast<const float2*>(&xs[rA * DIM + 2 * p]);
    float2 xvB = *reinterpret_cast<const float2*>(&xs[rB * DIM + 2 * p]);
    float vxA = fmaxf(fmaf(axA, idA, xvA.x), 0.f);
    float vyA = fmaxf(fmaf(ayA, idA, xvA.y), 0.f);
    float vxB = fmaxf(fmaf(axB, idB, xvB.x), 0.f);
    float vyB = fmaxf(fmaf(ayB, idB, xvB.y), 0.f);
    *reinterpret_cast<float2*>(&h[rA * DIM + 2 * p]) = make_float2(vxA, vyA);
    *reinterpret_cast<float2*>(&h[rB * DIM + 2 * p]) = make_float2(vxB, vyB);
    if constexpr (POOL) {
        int gA = gind[rA], gB = gind[rB];
        atomicAdd(&pooled[gA * DIM + 2 * p], vxA);
        atomicAdd(&pooled[gA * DIM + 2 * p + 1], vyA);
        atomicAdd(&pooled[gB * DIM + 2 * p], vxB);
        atomicAdd(&pooled[gB * DIM + 2 * p + 1], vyB);
    }
}

// ---------------------------------------------------------------- BN stats (sum, sumsq per channel)
__global__ void __launch_bounds__(256)
k_stats(const float* __restrict__ h, float* __restrict__ sums) {
    int lane = threadIdx.x & 63, w = threadIdx.x >> 6;
    float s = 0.f, q = 0.f;
    for (int r = blockIdx.x * 4 + w; r < N_NODES; r += gridDim.x * 4) {
        float v = h[r * DIM + lane];
        s += v;
        q = fmaf(v, v, q);
    }
    __shared__ float sS[4][DIM], sQ[4][DIM];
    sS[w][lane] = s; sQ[w][lane] = q;
    __syncthreads();
    if (w == 0) {
        float ts = sS[0][lane] + sS[1][lane] + sS[2][lane] + sS[3][lane];
        float tq = sQ[0][lane] + sQ[1][lane] + sQ[2][lane] + sQ[3][lane];
        atomicAdd(&sums[lane], ts);
        atomicAdd(&sums[DIM + lane], tq);
    }
}

// ---------------------------------------------------------------- BN finalize: a = g*rsqrt(var+eps), c = be - mean*a
__global__ void k_bnfin(const float* __restrict__ sums, const float* __restrict__ g,
                        const float* __restrict__ be, float* __restrict__ a,
                        float* __restrict__ c) {
    int t = threadIdx.x;  // 64 threads
    float m = sums[t] * (1.0f / N_NODES);
    float q = sums[DIM + t] * (1.0f / N_NODES);
    float v = q - m * m;
    float inv = 1.0f / sqrtf(v + EPS);
    float av = g[t] * inv;
    a[t] = av;
    c[t] = be[t] - m * av;
}

// ---------------------------------------------------------------- MLP head (one block per graph)
__global__ void __launch_bounds__(128)
k_mlp(const float* __restrict__ pooled,
      const float* __restrict__ W1, const float* __restrict__ b1,
      const float* __restrict__ W2, const float* __restrict__ b2,
      const float* __restrict__ W3, const float* __restrict__ b3,
      float* __restrict__ out) {
    __shared__ float sp[64], s1[128], s2[64];
    int g = blockIdx.x, t = threadIdx.x;
    if (t < 64) sp[t] = pooled[g * 64 + t];
    __syncthreads();
    {
        float acc = b1[t];
#pragma unroll
        for (int k = 0; k < 64; ++k) acc = fmaf(sp[k], W1[k * 128 + t], acc);
        s1[t] = fmaxf(acc, 0.f);
    }
    __syncthreads();
    if (t < 64) {
        float acc = b2[t];
#pragma unroll
        for (int k = 0; k < 128; ++k) acc = fmaf(s1[k], W2[k * 64 + t], acc);
        s2[t] = fmaxf(acc, 0.f);
    }
    __syncthreads();
    if (t < 10) {
        float acc = b3[t];
#pragma unroll
        for (int k = 0; k < 64; ++k) acc = fmaf(s2[k], W3[k * 10 + t], acc);
        out[g * 10 + t] = acc;
    }
}

// ---------------------------------------------------------------- launch
extern "C" void kernel_launch(void* const* d_in, const int* in_sizes, int n_in,
                              void* d_out, int out_size, void* d_ws, size_t ws_size,
                              hipStream_t stream) {
    const float* x0   = (const float*)d_in[0];
    const int* e_src  = (const int*)d_in[1];
    const int* e_dst  = (const int*)d_in[2];
    const int* gind   = (const int*)d_in[3];
    // d_in[4] = labels (unused)
    const float* Ws1 = (const float*)d_in[5],  *Wn1 = (const float*)d_in[6],  *b1 = (const float*)d_in[7];
    const float* Ws2 = (const float*)d_in[8],  *Wn2 = (const float*)d_in[9],  *b2 = (const float*)d_in[10];
    const float* Ws3 = (const float*)d_in[11], *Wn3 = (const float*)d_in[12], *b3 = (const float*)d_in[13];
    const float* g2  = (const float*)d_in[14], *be2 = (const float*)d_in[15];
    const float* g3  = (const float*)d_in[16], *be3 = (const float*)d_in[17];
    const float* fcW1 = (const float*)d_in[18], *fcb1 = (const float*)d_in[19];
    const float* fcW2 = (const float*)d_in[20], *fcb2 = (const float*)d_in[21];
    const float* fcW3 = (const float*)d_in[22], *fcb3 = (const float*)d_in[23];
    float* out = (float*)d_out;

    char* p = (char*)d_ws;
    auto carve = [&](size_t bytes) { void* r = (void*)p; p += (bytes + 255) & ~(size_t)255; return r; };
    int*   deg     = (int*)  carve(N_NODES * 4);
    int*   off     = (int*)  carve((N_NODES + 1) * 4);
    int*   csr_src = (int*)  carve(N_EDGES * 4);
    float* invd    = (float*)carve(N_NODES * 4);
    int*   bsum    = (int*)  carve(NSB * 4);
    int*   boff    = (int*)  carve((NSB + 1) * 4);
    int*   bcur    = (int*)  carve(NBUCK * 4);
    float* sums2   = (float*)carve(128 * 4);
    float* sums3   = (float*)carve(128 * 4);
    float* a2      = (float*)carve(64 * 4);
    float* c2      = (float*)carve(64 * 4);
    float* a3      = (float*)carve(64 * 4);
    float* c3      = (float*)carve(64 * 4);
    float* pooled  = (float*)carve(NUM_GRAPHS * DIM * 4);
    float* bufH    = (float*)carve((size_t)N_NODES * DIM * 4);
    float* bufXS   = (float*)carve((size_t)N_NODES * DIM * 4);
    unsigned* bufXN = (unsigned*)carve((size_t)N_NODES * 32 * 4);   // bf16-packed
    unsigned long long* ebuf = (unsigned long long*)carve((size_t)N_EDGES * 8);

    const int EB = (N_EDGES + 255) / 256;           // 3125
    const int GB = (N_NODES + GR - 1) / GR;         // 1563 (gemm: 32 rows/block)
    const int AB2 = N_NODES / 16;                   // 3125 (agg: 16 rows/block)

    k_zero<<<(N_NODES + 255) / 256, 256, 0, stream>>>(deg, sums2, sums3, pooled);
    k_count<<<EB, 256, 0, stream>>>(e_dst, deg);
    k_scan1<<<NSB, SB, 0, stream>>>(deg, bsum);
    k_scan2<<<1, 64, 0, stream>>>(bsum, boff);
    k_scan3<<<NSB, SB, 0, stream>>>(deg, boff, off, invd);
    k_bcinit<<<1, 256, 0, stream>>>(off, bcur);
    k_passA<<<PA_B, 1024, 0, stream>>>(e_src, e_dst, bcur, ebuf);
    k_passB<<<NBUCK, 1024, 0, stream>>>(ebuf, off, csr_src);

    // Layer 1 (no BN on input)
    k_gemm<false><<<GB, 256, 0, stream>>>(x0, Ws1, Wn1, b1, nullptr, nullptr,
                                          bufXS, (unsigned short*)bufXN);
    k_agg<false><<<AB2, 256, 0, stream>>>(bufXS, bufXN, off, csr_src, invd, nullptr, bufH, nullptr);

    // BN2 stats + Layer 2
    k_stats<<<240, 256, 0, stream>>>(bufH, sums2);
    k_bnfin<<<1, 64, 0, stream>>>(sums2, g2, be2, a2, c2);
    k_gemm<true><<<GB, 256, 0, stream>>>(bufH, Ws2, Wn2, b2, a2, c2,
                                         bufXS, (unsigned short*)bufXN);
    k_agg<false><<<AB2, 256, 0, stream>>>(bufXS, bufXN, off, csr_src, invd, nullptr, bufH, nullptr);

    // BN3 stats + Layer 3 (fused pooling)
    k_stats<<<240, 256, 0, stream>>>(bufH, sums3);
    k_bnfin<<<1, 64, 0, stream>>>(sums3, g3, be3, a3, c3);
    k_gemm<true><<<GB, 256, 0, stream>>>(bufH, Ws3, Wn3, b3, a3, c3,
                                         bufXS, (unsigned short*)bufXN);
    k_agg<true><<<AB2, 256, 0, stream>>>(bufXS, bufXN, off, csr_src, invd, gind, bufH, pooled);

    // MLP head
    k_mlp<<<NUM_GRAPHS, 128, 0, stream>>>(pooled, fcW1, fcb1, fcW2, fcb2, fcW3, fcb3, out);
}